// Round 5
// baseline (130.364 us; speedup 1.0000x reference)
//
#include <hip/hip_runtime.h>
#include <hip/hip_bf16.h>
#include <stdint.h>

typedef unsigned short u16;
typedef __attribute__((ext_vector_type(8))) short shortx8;
typedef __attribute__((ext_vector_type(4))) float floatx4;

#define N_ROWS 8192
#define N_COLS 512
#define KDIM   1024

__device__ __forceinline__ u16 f2bf(float f) {
    union { float f; uint32_t u; } x; x.f = f;
    uint32_t u = x.u;
    uint32_t r = (u + 0x7FFFu + ((u >> 16) & 1u)) >> 16;  // RNE
    return (u16)r;
}

// ---- kernel 1: protos prep -------------------------------------------------
// 128 blocks: protos->bf16 B[c][k]=(pr||pi) + |p|^2 (wave-per-class).
// Also zeroes d_out (runs before gemm_full's atomics).
__global__ __launch_bounds__(256) void prep(const float* __restrict__ protos,
                                            u16* __restrict__ bb,
                                            float* __restrict__ psq,
                                            float* __restrict__ out) {
    int t = threadIdx.x, lane = t & 63, w = t >> 6;
    if (blockIdx.x == 0 && t == 0) { out[0] = 0.0f; out[1] = 0.0f; }
    int c = blockIdx.x * 4 + w;               // 0..511
    const float4* pr = (const float4*)(protos + (size_t)c * 512);
    const float4* pi = (const float4*)(protos + 512 * 512 + (size_t)c * 512);
    ushort4* dr = (ushort4*)(bb + (size_t)c * KDIM);
    ushort4* di = (ushort4*)(bb + (size_t)c * KDIM + 512);
    float s = 0.0f;
    #pragma unroll
    for (int j = 0; j < 2; j++) {
        float4 a = pr[lane + j * 64];
        float4 b = pi[lane + j * 64];
        s += a.x * a.x + a.y * a.y + a.z * a.z + a.w * a.w;
        s += b.x * b.x + b.y * b.y + b.z * b.z + b.w * b.w;
        dr[lane + j * 64] = make_ushort4(f2bf(a.x), f2bf(a.y), f2bf(a.z), f2bf(a.w));
        di[lane + j * 64] = make_ushort4(f2bf(b.x), f2bf(b.y), f2bf(b.z), f2bf(b.w));
    }
    #pragma unroll
    for (int off = 32; off; off >>= 1) s += __shfl_xor(s, off);
    if (lane == 0) psq[c] = s;
}

// ---- kernel 2: full-row fused GEMM -----------------------------------------
// BM=32, BN=512 (all cols), BK=64, 512 threads (8 waves x 32rows-64cols),
// grid 256 = 1 block/CU. Per block:
//  * A: fp32 h loaded directly (4 VGPR prefetch), cvt bf16 in-register,
//    ds_write into the verified XOR-swizzled As layout. No hb buffer.
//  * B: fragments loaded straight from bb (1 MB, L2-resident) into MFMA
//    operands — no B LDS staging.
//  * Epilogue: full 512-col softmax/argmax per row completes in-block ->
//    atomicAdd(loss, acc). No partials, no combine kernel.
__global__ __launch_bounds__(512, 2) void gemm_full(const float* __restrict__ h,
                                                    const u16* __restrict__ bb,
                                                    const float* __restrict__ psq,
                                                    const float* __restrict__ radii,
                                                    const int* __restrict__ y,
                                                    const int* __restrict__ slab,
                                                    const int* __restrict__ ninit_p,
                                                    float* __restrict__ out) {
    constexpr int BK = 64, NSTEP = KDIM / BK;
    __shared__ __align__(16) u16 As[2][32 * BK];   // 2 x 4 KiB
    __shared__ float shsq[32];
    __shared__ float wmax[8][32];
    __shared__ int   wcol[8][32];
    __shared__ float wrm_[8][32];
    __shared__ float wc0_[8][32];
    __shared__ float wse_[8][32];
    __shared__ float sl0_[32];

    int t = threadIdx.x, lane = t & 63, w = t >> 6;   // w: 0..7
    int bm0 = blockIdx.x * 32;

    // ---- A staging mapping: thread t -> (row = t>>4, 4-float chunk = t&15) --
    int arow = t >> 4;              // 0..31
    int ac4  = t & 15;              // 16B fp32 chunk within 64-float K-step
    const float4* gA = (const float4*)(h + (size_t)(bm0 + arow) * KDIM) + ac4;
    // bf16 dest: 8-elem chunk kc=ac4>>1 stored at kc^(row&7), half ac4&1.
    int aoff = arow * BK + ((ac4 >> 1) ^ (arow & 7)) * 8 + (ac4 & 1) * 4;
    u16* asw[2] = { &As[0][aoff], &As[1][aoff] };

    // ---- fragment indices (verified layout) --------------------------------
    int kq = lane >> 4, m = lane & 15, l7 = lane & 7;
    int wc = w * 64;                // wave's 64-col slice
    int cols[4];
    const u16* gB[4];
    #pragma unroll
    for (int j = 0; j < 4; j++) {
        cols[j] = wc + 16 * j + m;
        gB[j] = bb + (size_t)cols[j] * KDIM + kq * 8;
    }
    int sw0 = (kq ^ l7) * 8;        // k-slice s=0 position within As row
    int sw1 = ((4 + kq) ^ l7) * 8;  // k-slice s=1
    const u16* paA0 = &As[0][m * BK];
    const u16* paA1 = &As[1][m * BK];

    floatx4 acc[2][4] = {};
    float hs = 0.0f;

    // ---- prologue: stage A tile 0 -----------------------------------------
    {
        float4 v = gA[0];
        hs += v.x * v.x + v.y * v.y + v.z * v.z + v.w * v.w;
        *(ushort4*)asw[0] = make_ushort4(f2bf(v.x), f2bf(v.y), f2bf(v.z), f2bf(v.w));
    }
    __syncthreads();

    // ---- main loop: one barrier per step ----------------------------------
    for (int step = 0; step < NSTEP; ++step) {
        int cur = step & 1;
        int k0 = step * BK;
        float4 av;
        bool pre = (step + 1 < NSTEP);
        if (pre) av = gA[(step + 1) * 16];          // 4-VGPR prefetch

        // B fragments straight from L2 (bb row-major, no swizzle needed)
        shortx8 bf0[4], bf1[4];
        #pragma unroll
        for (int j = 0; j < 4; j++) bf0[j] = *(const shortx8*)(gB[j] + k0);
        #pragma unroll
        for (int j = 0; j < 4; j++) bf1[j] = *(const shortx8*)(gB[j] + k0 + 32);

        // A fragments from LDS (verified swizzled read)
        const u16* paA = cur ? paA1 : paA0;
        shortx8 a00 = *(const shortx8*)(paA + sw0);
        shortx8 a01 = *(const shortx8*)(paA + 16 * BK + sw0);
        shortx8 a10 = *(const shortx8*)(paA + sw1);
        shortx8 a11 = *(const shortx8*)(paA + 16 * BK + sw1);

        #pragma unroll
        for (int j = 0; j < 4; j++) {
            acc[0][j] = __builtin_amdgcn_mfma_f32_16x16x32_bf16(a00, bf0[j], acc[0][j], 0, 0, 0);
            acc[1][j] = __builtin_amdgcn_mfma_f32_16x16x32_bf16(a01, bf0[j], acc[1][j], 0, 0, 0);
        }
        #pragma unroll
        for (int j = 0; j < 4; j++) {
            acc[0][j] = __builtin_amdgcn_mfma_f32_16x16x32_bf16(a10, bf1[j], acc[0][j], 0, 0, 0);
            acc[1][j] = __builtin_amdgcn_mfma_f32_16x16x32_bf16(a11, bf1[j], acc[1][j], 0, 0, 0);
        }

        if (pre) {                  // cvt + stage A(t+1) into the other buffer
            hs += av.x * av.x + av.y * av.y + av.z * av.z + av.w * av.w;
            *(ushort4*)asw[cur ^ 1] =
                make_ushort4(f2bf(av.x), f2bf(av.y), f2bf(av.z), f2bf(av.w));
        }
        __syncthreads();            // As(t+1) visible; all reads of As(t) done
    }

    // ---- hsq: reduce 16 chunk-partials per row -----------------------------
    hs += __shfl_xor(hs, 1);
    hs += __shfl_xor(hs, 2);
    hs += __shfl_xor(hs, 4);
    hs += __shfl_xor(hs, 8);
    if (ac4 == 0) shsq[arow] = hs;
    __syncthreads();

    // ---- epilogue: per-wave 64-col reduction -------------------------------
    float psqv[4], invv[4]; int slv[4];
    #pragma unroll
    for (int j = 0; j < 4; j++) {
        psqv[j] = psq[cols[j]];
        invv[j] = 0.5f / radii[cols[j]];
        slv[j]  = slab[cols[j]];
    }
    int slabz = slab[0];
    int ninit = ninit_p[0];

    #pragma unroll
    for (int i = 0; i < 2; i++) {
        #pragma unroll
        for (int r = 0; r < 4; r++) {
            int lr = i * 16 + kq * 4 + r;          // row within block (0..31)
            float hsqn = shsq[lr];
            int yv = y[bm0 + lr];
            int lab = (yv >= ninit) ? -1 : yv;
            float v[4];
            #pragma unroll
            for (int j = 0; j < 4; j++)
                v[j] = (2.0f * acc[i][j][r] - hsqn - psqv[j]) * invv[j];
            if (w == 0 && m == 0) sl0_[lr] = v[0]; // logits[n][0]

            float bmax = v[0]; int bcol = cols[0];
            #pragma unroll
            for (int j = 1; j < 4; j++)
                if (v[j] > bmax) { bmax = v[j]; bcol = cols[j]; }  // cols asc
            float brm = -INFINITY, bc0 = -INFINITY;
            #pragma unroll
            for (int j = 0; j < 4; j++) {
                if (slv[j] == lab   && v[j] > brm) brm = v[j];
                if (slv[j] == slabz && v[j] > bc0) bc0 = v[j];
            }
            #pragma unroll
            for (int off = 1; off < 16; off <<= 1) {   // merge over m
                float ov = __shfl_xor(bmax, off); int oc = __shfl_xor(bcol, off);
                if (ov > bmax || (ov == bmax && oc < bcol)) { bmax = ov; bcol = oc; }
                float orv = __shfl_xor(brm, off); if (orv > brm) brm = orv;
                float oc0 = __shfl_xor(bc0, off); if (oc0 > bc0) bc0 = oc0;
            }
            float se = __expf(v[0] - bmax) + __expf(v[1] - bmax)
                     + __expf(v[2] - bmax) + __expf(v[3] - bmax);
            #pragma unroll
            for (int off = 1; off < 16; off <<= 1) se += __shfl_xor(se, off);
            if (m == 0) {
                wmax[w][lr] = bmax; wcol[w][lr] = bcol;
                wrm_[w][lr] = brm;  wc0_[w][lr] = bc0; wse_[w][lr] = se;
            }
        }
    }
    __syncthreads();

    // ---- final: merge 8 waves per row, loss/acc, block atomic --------------
    if (t < 32) {
        int n = bm0 + t;
        float gm = -INFINITY; int gi = 0x7fffffff;
        float rm = -INFINITY, c0m = -INFINITY;
        float wm[8];
        #pragma unroll
        for (int w2 = 0; w2 < 8; w2++) {
            float p = wmax[w2][t]; int pi = wcol[w2][t];
            wm[w2] = p;
            if (p > gm || (p == gm && pi < gi)) { gm = p; gi = pi; }
            float orv = wrm_[w2][t]; if (orv > rm) rm = orv;
            float oc0 = wc0_[w2][t]; if (oc0 > c0m) c0m = oc0;
        }
        float den = 0.0f;
        #pragma unroll
        for (int w2 = 0; w2 < 8; w2++)
            den += wse_[w2][t] * __expf(wm[w2] - gm);
        float lse = gm + __logf(den);

        int yv = y[n];
        int lab = (yv >= ninit) ? -1 : yv;
        float nll, wgt;
        if (rm != -INFINITY) { nll = lse - rm; wgt = 1.0f; }
        else {
            float l0 = sl0_[t];
            nll = lse - l0;
            wgt = (l0 == c0m) ? 1.0f : 0.0f;
        }
        int ypred = slab[gi];
        float li = nll * wgt * (1.0f / (float)N_ROWS);
        float ai = (ypred == lab) ? 1.0f : 0.0f;
        #pragma unroll
        for (int off = 16; off; off >>= 1) {
            li += __shfl_xor(li, off);
            ai += __shfl_xor(ai, off);
        }
        if (t == 0) {
            atomicAdd(&out[0], li);
            atomicAdd(&out[1], ai);
        }
    }
}

extern "C" void kernel_launch(void* const* d_in, const int* in_sizes, int n_in,
                              void* d_out, int out_size, void* d_ws, size_t ws_size,
                              hipStream_t stream) {
    const float* h      = (const float*)d_in[0];
    const float* protos = (const float*)d_in[1];
    const float* radii  = (const float*)d_in[2];
    const int*   y      = (const int*)d_in[3];
    const int*   slab   = (const int*)d_in[4];
    const int*   ninit  = (const int*)d_in[5];
    float* out = (float*)d_out;

    char* ws = (char*)d_ws;
    u16*   bb  = (u16*)(ws);                 // 1 MiB
    float* psq = (float*)(ws + 1048576);     // 2 KiB

    prep<<<128, 256, 0, stream>>>(protos, bb, psq, out);
    gemm_full<<<256, 512, 0, stream>>>(h, bb, psq, radii, y, slab, ninit, out);
}

// Round 6
// 120.530 us; speedup vs baseline: 1.0816x; 1.0816x over previous
//
#include <hip/hip_runtime.h>
#include <stdint.h>

typedef unsigned short u16;
typedef __attribute__((ext_vector_type(8))) short shortx8;
typedef __attribute__((ext_vector_type(4))) float floatx4;

#define N_ROWS 8192
#define N_COLS 512
#define KDIM   1024

__device__ __forceinline__ u16 f2bf(float f) {
    union { float f; uint32_t u; } x; x.f = f;
    uint32_t u = x.u;
    uint32_t r = (u + 0x7FFFu + ((u >> 16) & 1u)) >> 16;  // RNE
    return (u16)r;
}

__device__ __forceinline__ void async_copy16(const void* g, void* l) {
    __builtin_amdgcn_global_load_lds(
        (const __attribute__((address_space(1))) void*)g,
        (__attribute__((address_space(3))) void*)l, 16, 0, 0);
}

// pack 2 f32 -> u32 of 2 bf16 (RNE), hw instruction
__device__ __forceinline__ uint32_t cvt_pk_bf16(float lo, float hi) {
    uint32_t r;
    asm("v_cvt_pk_bf16_f32 %0, %1, %2" : "=v"(r) : "v"(lo), "v"(hi));
    return r;
}

// ---- kernel 1: protos prep + out zero --------------------------------------
__global__ __launch_bounds__(256) void prep(const float* __restrict__ protos,
                                            u16* __restrict__ bb,
                                            float* __restrict__ psq,
                                            float* __restrict__ out) {
    int t = threadIdx.x, lane = t & 63, w = t >> 6;
    if (blockIdx.x == 0 && t == 0) { out[0] = 0.0f; out[1] = 0.0f; }
    int c = blockIdx.x * 4 + w;               // 0..511
    const float4* pr = (const float4*)(protos + (size_t)c * 512);
    const float4* pi = (const float4*)(protos + 512 * 512 + (size_t)c * 512);
    ushort4* dr = (ushort4*)(bb + (size_t)c * KDIM);
    ushort4* di = (ushort4*)(bb + (size_t)c * KDIM + 512);
    float s = 0.0f;
    #pragma unroll
    for (int j = 0; j < 2; j++) {
        float4 a = pr[lane + j * 64];
        float4 b = pi[lane + j * 64];
        s += a.x * a.x + a.y * a.y + a.z * a.z + a.w * a.w;
        s += b.x * b.x + b.y * b.y + b.z * b.z + b.w * b.w;
        dr[lane + j * 64] = make_ushort4(f2bf(a.x), f2bf(a.y), f2bf(a.z), f2bf(a.w));
        di[lane + j * 64] = make_ushort4(f2bf(b.x), f2bf(b.y), f2bf(b.z), f2bf(b.w));
    }
    #pragma unroll
    for (int off = 32; off; off >>= 1) s += __shfl_xor(s, off);
    if (lane == 0) psq[c] = s;
}

// ---- kernel 2: fused fp32-A GEMM + logits + row-partials -------------------
// BM=128, BN=64, BK=64, 256 threads (4 waves each 64x32), 512 blocks.
// Round-1's PROVEN structure (global_load_lds -> LDS -> ds_read_b128 -> MFMA,
// 2 barriers/step). Change: A is staged as fp32 straight from h (no hb
// round-trip, no conv h-pass). fp32->bf16 cvt happens at fragment read via
// v_cvt_pk_bf16_f32; hsq accumulated in-register from the same fragments.
// A LDS layout: 16B chunk c of row r stored at position c^(r&15), applied by
// pre-swizzling the GLOBAL source chunk (linear LDS dest per rule #21).
__global__ __launch_bounds__(256) void gemm_fused(const float* __restrict__ h,
                                                  const u16* __restrict__ bb,
                                                  const float* __restrict__ psq,
                                                  const float* __restrict__ radii,
                                                  const int* __restrict__ y,
                                                  const int* __restrict__ slab,
                                                  const int* __restrict__ ninit_p,
                                                  float* __restrict__ pmax_g,
                                                  int* __restrict__ pidx_g,
                                                  float* __restrict__ prmax_g,
                                                  float* __restrict__ pc0_g,
                                                  float* __restrict__ psum_g,
                                                  float* __restrict__ l0arr) {
    constexpr int BM = 128, BN = 64, BK = 64, NSTEP = KDIM / BK;
    __shared__ __align__(16) float Asf[BM * BK];   // 32 KiB fp32 A tile
    __shared__ __align__(16) u16 Bs[BN * BK];      // 8 KiB bf16 B tile
    __shared__ float shsq[BM];
    __shared__ float smax[2][128];
    __shared__ int   scol[2][128];
    __shared__ float srmx[2][128];
    __shared__ float sc0v[2][128];
    __shared__ float ssum[2][128];

    int t = threadIdx.x, lane = t & 63, w = t >> 6;
    int wr = (w & 1) * 64;          // wave row offset
    int wc = (w >> 1) * 32;         // wave col offset

    // XCD swizzle (bijective, 512 % 8 == 0)
    int bid = blockIdx.x;
    int xcd = bid & 7;
    int idin = bid >> 3;
    int bx = (xcd << 3) | (idin >> 3);
    int by = idin & 7;
    int bm0 = bx * BM;
    int bn0 = by * BN;

    // A staging: slot s = t + 256*i -> row = s>>4 (= t>>4 + 16i), chunk-pos
    // cpos = t&15. Position cpos holds GLOBAL chunk cg = cpos ^ (row&15);
    // row&15 == t>>4 for all i, so cg is constant per thread.
    int arow0 = t >> 4;             // 0..15
    int cg = (t & 15) ^ arow0;
    const float* gA = h + (size_t)(bm0 + arow0) * KDIM + cg * 4;
    float* lA = &Asf[t * 4];        // + i*1024 floats

    // B staging (round-1 verified): slot s -> row = s>>3, stored kchunk (s&7)
    // holds global kchunk (s&7)^(row&7).
    int tr = t >> 3, tc = t & 7;
    const u16* gB[2]; int lBoff[2];
    #pragma unroll
    for (int i = 0; i < 2; i++) {
        int row = tr + 32 * i;
        int kc = tc ^ (row & 7);
        gB[i] = bb + (size_t)(bn0 + row) * KDIM + kc * 8;
        lBoff[i] = (t + 256 * i) * 8;
    }

    floatx4 acc[4][2] = {};
    float hs[4] = {0.0f, 0.0f, 0.0f, 0.0f};
    int kq = lane >> 4, l7 = lane & 7, m = lane & 15;
    const u16* paB = &Bs[(wc + m) * BK];

    for (int step = 0; step < NSTEP; ++step) {
        __syncthreads();
        #pragma unroll
        for (int i = 0; i < 8; i++)
            async_copy16(gA + (size_t)i * 16 * KDIM + step * BK, lA + i * 1024);
        #pragma unroll
        for (int i = 0; i < 2; i++)
            async_copy16(gB[i] + step * BK, &Bs[lBoff[i]]);
        __syncthreads();            // drain DMA

        #pragma unroll
        for (int s = 0; s < 2; s++) {
            int g = s * 4 + kq;     // 8-float k-group within BK
            shortx8 af[4], bf[2];
            #pragma unroll
            for (int i = 0; i < 4; i++) {
                const float* rowp = &Asf[(wr + i * 16 + m) * BK];
                float4 fa = *(const float4*)(rowp + (((2 * g)     ^ m) * 4));
                float4 fb = *(const float4*)(rowp + (((2 * g + 1) ^ m) * 4));
                hs[i] += fa.x * fa.x + fa.y * fa.y + fa.z * fa.z + fa.w * fa.w
                       + fb.x * fb.x + fb.y * fb.y + fb.z * fb.z + fb.w * fb.w;
                union { shortx8 v; uint32_t u[4]; } pk;
                pk.u[0] = cvt_pk_bf16(fa.x, fa.y);
                pk.u[1] = cvt_pk_bf16(fa.z, fa.w);
                pk.u[2] = cvt_pk_bf16(fb.x, fb.y);
                pk.u[3] = cvt_pk_bf16(fb.z, fb.w);
                af[i] = pk.v;
            }
            int sw = (g ^ l7) * 8;
            #pragma unroll
            for (int jj = 0; jj < 2; jj++)
                bf[jj] = *(const shortx8*)(paB + jj * 16 * BK + sw);
            #pragma unroll
            for (int i = 0; i < 4; i++)
                #pragma unroll
                for (int jj = 0; jj < 2; jj++)
                    acc[i][jj] = __builtin_amdgcn_mfma_f32_16x16x32_bf16(af[i], bf[jj], acc[i][jj], 0, 0, 0);
        }
    }

    // ---- hsq: lane's fragments covered k-groups {kq, 4+kq} of every step;
    // reduce over the 4 kq-lanes (bits 4,5) -> rows wr + i*16 + m complete.
    // Waves 0/2 and 1/3 duplicate rows; only w<2 writes.
    #pragma unroll
    for (int i = 0; i < 4; i++) {
        float v = hs[i];
        v += __shfl_xor(v, 16);
        v += __shfl_xor(v, 32);
        if (w < 2 && kq == 0) shsq[wr + i * 16 + m] = v;
    }
    __syncthreads();

    // ---- epilogue: logits in-register, reduce 64 cols -> per-row partials --
    int c0 = bn0 + wc + m, c1 = c0 + 16;
    float ps0 = psq[c0], ps1 = psq[c1];
    float inv0 = 0.5f / radii[c0], inv1 = 0.5f / radii[c1];
    int sl0 = slab[c0], sl1 = slab[c1];
    int slabz = slab[0];
    int ninit = ninit_p[0];
    int ch = w >> 1;                 // column half within block
    bool isL0 = (bn0 == 0) && (wc == 0) && (m == 0);

    #pragma unroll
    for (int i = 0; i < 4; i++) {
        #pragma unroll
        for (int r = 0; r < 4; r++) {
            int lr = wr + i * 16 + kq * 4 + r;
            int n = bm0 + lr;
            float hsqn = shsq[lr];
            int yv = y[n];
            int lab = (yv >= ninit) ? -1 : yv;
            float v0 = (2.0f * acc[i][0][r] - hsqn - ps0) * inv0;
            float v1 = (2.0f * acc[i][1][r] - hsqn - ps1) * inv1;
            if (isL0) l0arr[n] = v0;                 // logits[n][0]

            float bmax = v0; int bcol = c0;
            if (v1 > bmax) { bmax = v1; bcol = c1; } // tie keeps lower col
            float brm = -INFINITY;
            if (sl0 == lab) brm = v0;
            if (sl1 == lab && v1 > brm) brm = v1;
            float bc0 = -INFINITY;
            if (sl0 == slabz) bc0 = v0;
            if (sl1 == slabz && v1 > bc0) bc0 = v1;
            #pragma unroll
            for (int off = 1; off < 16; off <<= 1) {   // reduce over m (16 lanes)
                float ov = __shfl_xor(bmax, off); int oc = __shfl_xor(bcol, off);
                if (ov > bmax || (ov == bmax && oc < bcol)) { bmax = ov; bcol = oc; }
                float orv = __shfl_xor(brm, off); if (orv > brm) brm = orv;
                float oc0 = __shfl_xor(bc0, off); if (oc0 > bc0) bc0 = oc0;
            }
            float se = __expf(v0 - bmax) + __expf(v1 - bmax);
            #pragma unroll
            for (int off = 1; off < 16; off <<= 1) se += __shfl_xor(se, off);
            if (m == 0) {
                int rl = (w & 1) * 64 + i * 16 + kq * 4 + r;
                smax[ch][rl] = bmax; scol[ch][rl] = bcol;
                srmx[ch][rl] = brm;  sc0v[ch][rl] = bc0; ssum[ch][rl] = se;
            }
        }
    }
    __syncthreads();
    if (t < 128) {                    // merge the two 32-col halves, write
        int n = bm0 + t;
        size_t gi_ = (size_t)by * N_ROWS + n;
        float m0 = smax[0][t], m1 = smax[1][t];
        int i0 = scol[0][t], i1 = scol[1][t];
        float gm; int gi;
        if (m0 > m1 || (m0 == m1 && i0 < i1)) { gm = m0; gi = i0; }
        else { gm = m1; gi = i1; }
        pmax_g[gi_] = gm;
        pidx_g[gi_] = gi;
        prmax_g[gi_] = fmaxf(srmx[0][t], srmx[1][t]);
        pc0_g[gi_]  = fmaxf(sc0v[0][t], sc0v[1][t]);
        psum_g[gi_] = ssum[0][t] * __expf(m0 - gm) + ssum[1][t] * __expf(m1 - gm);
    }
}

// ---- kernel 3: combine 8 column-block partials per row -> loss, acc --------
__global__ __launch_bounds__(256) void combine(const float* __restrict__ pmax_g,
                                               const int* __restrict__ pidx_g,
                                               const float* __restrict__ prmax_g,
                                               const float* __restrict__ pc0_g,
                                               const float* __restrict__ psum_g,
                                               const float* __restrict__ l0arr,
                                               const int* __restrict__ y,
                                               const int* __restrict__ slab,
                                               const int* __restrict__ ninit_p,
                                               float* __restrict__ out) {
    int t = threadIdx.x, lane = t & 63, w = t >> 6;
    int n = blockIdx.x * 256 + t;

    float gm = -INFINITY; int gi = 0x7fffffff;
    float rm = -INFINITY, c0m = -INFINITY;
    float pm[8];
    #pragma unroll
    for (int cb = 0; cb < 8; cb++) {
        size_t idx = (size_t)cb * N_ROWS + n;
        float p = pmax_g[idx]; int pi = pidx_g[idx];
        pm[cb] = p;
        if (p > gm || (p == gm && pi < gi)) { gm = p; gi = pi; }
        rm = fmaxf(rm, prmax_g[idx]);
        c0m = fmaxf(c0m, pc0_g[idx]);
    }
    float den = 0.0f;
    #pragma unroll
    for (int cb = 0; cb < 8; cb++)
        den += psum_g[(size_t)cb * N_ROWS + n] * __expf(pm[cb] - gm);
    float lse = gm + __logf(den);

    int yv = y[n];
    int lab = (yv >= ninit_p[0]) ? -1 : yv;
    float nll, wgt;
    if (rm != -INFINITY) { nll = lse - rm; wgt = 1.0f; }
    else {                                   // all-(-inf) argmax -> col 0
        float l0 = l0arr[n];
        nll = lse - l0;
        wgt = (l0 == c0m) ? 1.0f : 0.0f;
    }
    int ypred = slab[gi];
    float li = nll * wgt * (1.0f / (float)N_ROWS);
    float ai = (ypred == lab) ? 1.0f : 0.0f;

    #pragma unroll
    for (int off = 32; off; off >>= 1) {
        li += __shfl_xor(li, off);
        ai += __shfl_xor(ai, off);
    }
    __shared__ float pl[4], pa_[4];
    if (lane == 0) { pl[w] = li; pa_[w] = ai; }
    __syncthreads();
    if (t == 0) {
        atomicAdd(&out[0], pl[0] + pl[1] + pl[2] + pl[3]);
        atomicAdd(&out[1], pa_[0] + pa_[1] + pa_[2] + pa_[3]);
    }
}

extern "C" void kernel_launch(void* const* d_in, const int* in_sizes, int n_in,
                              void* d_out, int out_size, void* d_ws, size_t ws_size,
                              hipStream_t stream) {
    const float* h      = (const float*)d_in[0];
    const float* protos = (const float*)d_in[1];
    const float* radii  = (const float*)d_in[2];
    const int*   y      = (const int*)d_in[3];
    const int*   slab   = (const int*)d_in[4];
    const int*   ninit  = (const int*)d_in[5];
    float* out = (float*)d_out;

    char* ws = (char*)d_ws;
    u16*   bb    = (u16*)(ws);                       // 1 MiB
    float* psq   = (float*)(ws + 1048576);           // 2 KiB
    float* pmax  = (float*)(ws + 1050624);           // 256 KiB each
    int*   pidx  = (int*)  (ws + 1312768);
    float* prmax = (float*)(ws + 1574912);
    float* pc0   = (float*)(ws + 1837056);
    float* psum  = (float*)(ws + 2099200);
    float* l0arr = (float*)(ws + 2361344);           // 32 KiB

    prep<<<128, 256, 0, stream>>>(protos, bb, psq, out);
    gemm_fused<<<512, 256, 0, stream>>>(h, bb, psq, radii, y, slab, ninit,
                                        pmax, pidx, prmax, pc0, psum, l0arr);
    combine<<<N_ROWS / 256, 256, 0, stream>>>(pmax, pidx, prmax, pc0, psum,
                                              l0arr, y, slab, ninit, out);
}

// Round 8
// 117.342 us; speedup vs baseline: 1.1110x; 1.0272x over previous
//
#include <hip/hip_runtime.h>
#include <stdint.h>

typedef unsigned short u16;
typedef __attribute__((ext_vector_type(8))) short shortx8;
typedef __attribute__((ext_vector_type(4))) float floatx4;

#define N_ROWS 8192
#define N_COLS 512
#define KDIM   1024

__device__ __forceinline__ u16 f2bf(float f) {
    union { float f; uint32_t u; } x; x.f = f;
    uint32_t u = x.u;
    uint32_t r = (u + 0x7FFFu + ((u >> 16) & 1u)) >> 16;  // RNE
    return (u16)r;
}

__device__ __forceinline__ void async_copy16(const void* g, void* l) {
    __builtin_amdgcn_global_load_lds(
        (const __attribute__((address_space(1))) void*)g,
        (__attribute__((address_space(3))) void*)l, 16, 0, 0);
}

// ---- kernel 1: fused input prep --------------------------------------------
// blocks [0,512): h fp32->bf16 + row |h|^2 (wave-per-row, 4 rows/wave)
// blocks [512,640): protos->bf16 B[c][k]=(pr||pi) + |p|^2 (wave-per-class)
// Also zeroes d_out (runs before combine's atomics; saves a memset dispatch).
__global__ __launch_bounds__(256) void conv_hp(const float* __restrict__ h,
                                               const float* __restrict__ protos,
                                               u16* __restrict__ hb,
                                               u16* __restrict__ bb,
                                               float* __restrict__ hsq,
                                               float* __restrict__ psq,
                                               float* __restrict__ out) {
    int t = threadIdx.x, lane = t & 63, w = t >> 6;
    int bid = blockIdx.x;
    if (bid == 0 && t == 0) { out[0] = 0.0f; out[1] = 0.0f; }
    if (bid < 512) {
        int wave = bid * 4 + w;                    // 0..2047
        for (int q = 0; q < 4; q++) {
            int row = wave * 4 + q;
            const float4* src = (const float4*)(h + (size_t)row * KDIM);
            ushort4* dst = (ushort4*)(hb + (size_t)row * KDIM);
            float s = 0.0f;
            #pragma unroll
            for (int j = 0; j < 4; j++) {
                float4 v = src[lane + j * 64];
                s += v.x * v.x + v.y * v.y + v.z * v.z + v.w * v.w;
                dst[lane + j * 64] = make_ushort4(f2bf(v.x), f2bf(v.y), f2bf(v.z), f2bf(v.w));
            }
            #pragma unroll
            for (int off = 32; off; off >>= 1) s += __shfl_xor(s, off);
            if (lane == 0) hsq[row] = s;
        }
    } else {
        int c = (bid - 512) * 4 + w;               // 0..511
        const float4* pr = (const float4*)(protos + (size_t)c * 512);
        const float4* pi = (const float4*)(protos + 512 * 512 + (size_t)c * 512);
        ushort4* dr = (ushort4*)(bb + (size_t)c * KDIM);
        ushort4* di = (ushort4*)(bb + (size_t)c * KDIM + 512);
        float s = 0.0f;
        #pragma unroll
        for (int j = 0; j < 2; j++) {
            float4 a = pr[lane + j * 64];
            float4 b = pi[lane + j * 64];
            s += a.x * a.x + a.y * a.y + a.z * a.z + a.w * a.w;
            s += b.x * b.x + b.y * b.y + b.z * b.z + b.w * b.w;
            dr[lane + j * 64] = make_ushort4(f2bf(a.x), f2bf(a.y), f2bf(a.z), f2bf(a.w));
            di[lane + j * 64] = make_ushort4(f2bf(b.x), f2bf(b.y), f2bf(b.z), f2bf(b.w));
        }
        #pragma unroll
        for (int off = 32; off; off >>= 1) s += __shfl_xor(s, off);
        if (lane == 0) psq[c] = s;
    }
}

// ---- kernel 2: bf16 MFMA GEMM + fused logits + row-partial reduction -------
// BM=128, BN=64, BK=64, 256 threads (4 waves, each 64x32), 512 blocks 1D.
__global__ __launch_bounds__(256) void gemm_partials(const u16* __restrict__ hb,
                                                     const u16* __restrict__ bb,
                                                     const float* __restrict__ hsq,
                                                     const float* __restrict__ psq,
                                                     const float* __restrict__ radii,
                                                     const int* __restrict__ y,
                                                     const int* __restrict__ slab,
                                                     const int* __restrict__ ninit_p,
                                                     float* __restrict__ pmax_g,
                                                     int* __restrict__ pidx_g,
                                                     float* __restrict__ prmax_g,
                                                     float* __restrict__ pc0_g,
                                                     float* __restrict__ psum_g,
                                                     float* __restrict__ l0arr) {
    constexpr int BM = 128, BN = 64, BK = 64;
    __shared__ __align__(16) u16 As[BM * BK];   // 16 KiB
    __shared__ __align__(16) u16 Bs[BN * BK];   // 8 KiB
    __shared__ float smax[2][128];
    __shared__ int   scol[2][128];
    __shared__ float srmx[2][128];
    __shared__ float sc0v[2][128];
    __shared__ float ssum[2][128];

    int t = threadIdx.x, lane = t & 63, w = t >> 6;
    int wr = (w & 1) * 64;          // wave row offset
    int wc = (w >> 1) * 32;         // wave col offset

    // XCD swizzle (bijective, 512 % 8 == 0)
    int bid = blockIdx.x;
    int xcd = bid & 7;
    int idin = bid >> 3;
    int bx = (xcd << 3) | (idin >> 3);
    int by = idin & 7;
    int bm0 = bx * BM;
    int bn0 = by * BN;

    // staging slots: slot s -> row = s>>3, stored kchunk (s&7) holds global
    // kchunk (s&7)^(row&7).
    int tr = t >> 3, tc = t & 7;
    const u16* gA[4]; u16* lA[4];
    #pragma unroll
    for (int i = 0; i < 4; i++) {
        int row = tr + 32 * i;
        int kc = tc ^ (row & 7);
        gA[i] = hb + (size_t)(bm0 + row) * KDIM + kc * 8;
        lA[i] = &As[(t + 256 * i) * 8];
    }
    const u16* gB[2]; u16* lB[2];
    #pragma unroll
    for (int i = 0; i < 2; i++) {
        int row = tr + 32 * i;
        int kc = tc ^ (row & 7);
        gB[i] = bb + (size_t)(bn0 + row) * KDIM + kc * 8;
        lB[i] = &Bs[(t + 256 * i) * 8];
    }

    floatx4 acc[4][2] = {};

    int kq = lane >> 4, l7 = lane & 7, m = lane & 15;
    int swz0 = ((kq) ^ l7) * 8;
    int swz1 = ((4 + kq) ^ l7) * 8;
    const u16* paA = &As[(wr + m) * BK];
    const u16* paB = &Bs[(wc + m) * BK];

    for (int k0 = 0; k0 < KDIM; k0 += BK) {
        __syncthreads();
        #pragma unroll
        for (int i = 0; i < 4; i++) async_copy16(gA[i], lA[i]);
        #pragma unroll
        for (int i = 0; i < 2; i++) async_copy16(gB[i], lB[i]);
        #pragma unroll
        for (int i = 0; i < 4; i++) gA[i] += BK;
        #pragma unroll
        for (int i = 0; i < 2; i++) gB[i] += BK;
        __syncthreads();

        #pragma unroll
        for (int s = 0; s < 2; s++) {
            int sw = s ? swz1 : swz0;
            shortx8 af[4], bf[2];
            #pragma unroll
            for (int i = 0; i < 4; i++) af[i] = *(const shortx8*)(paA + i * 16 * BK + sw);
            #pragma unroll
            for (int j = 0; j < 2; j++) bf[j] = *(const shortx8*)(paB + j * 16 * BK + sw);
            #pragma unroll
            for (int i = 0; i < 4; i++)
                #pragma unroll
                for (int j = 0; j < 2; j++)
                    acc[i][j] = __builtin_amdgcn_mfma_f32_16x16x32_bf16(af[i], bf[j], acc[i][j], 0, 0, 0);
        }
    }

    // ---- epilogue: logits in-register, reduce 64 cols -> per-row partials --
    // C/D: col = lane&15 (=m), row = kq*4 + reg. Lane's 2 cols:
    int c0 = bn0 + wc + m, c1 = c0 + 16;
    float ps0 = psq[c0], ps1 = psq[c1];
    float inv0 = 0.5f / radii[c0], inv1 = 0.5f / radii[c1];
    int sl0 = slab[c0], sl1 = slab[c1];
    int slabz = slab[0];
    int ninit = ninit_p[0];
    int ch = w >> 1;                 // column half within block
    bool isL0 = (bn0 == 0) && (wc == 0) && (m == 0);

    #pragma unroll
    for (int i = 0; i < 4; i++) {
        #pragma unroll
        for (int r = 0; r < 4; r++) {
            int n = bm0 + wr + i * 16 + kq * 4 + r;
            float hsqn = hsq[n];
            int yv = y[n];
            int lab = (yv >= ninit) ? -1 : yv;
            float v0 = (2.0f * acc[i][0][r] - hsqn - ps0) * inv0;
            float v1 = (2.0f * acc[i][1][r] - hsqn - ps1) * inv1;
            if (isL0) l0arr[n] = v0;                 // logits[n][0]

            float bmax = v0; int bcol = c0;
            if (v1 > bmax) { bmax = v1; bcol = c1; } // tie keeps lower col
            float brm = -INFINITY;
            if (sl0 == lab) brm = v0;
            if (sl1 == lab && v1 > brm) brm = v1;
            float bc0 = -INFINITY;
            if (sl0 == slabz) bc0 = v0;
            if (sl1 == slabz && v1 > bc0) bc0 = v1;
            #pragma unroll
            for (int off = 1; off < 16; off <<= 1) {   // reduce over m (16 lanes)
                float ov = __shfl_xor(bmax, off); int oc = __shfl_xor(bcol, off);
                if (ov > bmax || (ov == bmax && oc < bcol)) { bmax = ov; bcol = oc; }
                float orv = __shfl_xor(brm, off); if (orv > brm) brm = orv;
                float oc0 = __shfl_xor(bc0, off); if (oc0 > bc0) bc0 = oc0;
            }
            float se = __expf(v0 - bmax) + __expf(v1 - bmax);
            #pragma unroll
            for (int off = 1; off < 16; off <<= 1) se += __shfl_xor(se, off);
            if (m == 0) {
                int rl = (w & 1) * 64 + i * 16 + kq * 4 + r;
                smax[ch][rl] = bmax; scol[ch][rl] = bcol;
                srmx[ch][rl] = brm;  sc0v[ch][rl] = bc0; ssum[ch][rl] = se;
            }
        }
    }
    __syncthreads();
    if (t < 128) {                    // merge the two 32-col halves, write
        int n = bm0 + t;
        size_t gi_ = (size_t)by * N_ROWS + n;
        float m0 = smax[0][t], m1 = smax[1][t];
        int i0 = scol[0][t], i1 = scol[1][t];
        float gm; int gi;
        if (m0 > m1 || (m0 == m1 && i0 < i1)) { gm = m0; gi = i0; }
        else { gm = m1; gi = i1; }
        pmax_g[gi_] = gm;
        pidx_g[gi_] = gi;
        prmax_g[gi_] = fmaxf(srmx[0][t], srmx[1][t]);
        pc0_g[gi_]  = fmaxf(sc0v[0][t], sc0v[1][t]);
        psum_g[gi_] = ssum[0][t] * __expf(m0 - gm) + ssum[1][t] * __expf(m1 - gm);
    }
}

// ---- kernel 3: combine 8 column-block partials per row -> loss, acc --------
__global__ __launch_bounds__(256) void combine(const float* __restrict__ pmax_g,
                                               const int* __restrict__ pidx_g,
                                               const float* __restrict__ prmax_g,
                                               const float* __restrict__ pc0_g,
                                               const float* __restrict__ psum_g,
                                               const float* __restrict__ l0arr,
                                               const int* __restrict__ y,
                                               const int* __restrict__ slab,
                                               const int* __restrict__ ninit_p,
                                               float* __restrict__ out) {
    int t = threadIdx.x, lane = t & 63, w = t >> 6;
    int n = blockIdx.x * 256 + t;

    float gm = -INFINITY; int gi = 0x7fffffff;
    float rm = -INFINITY, c0m = -INFINITY;
    float pm[8];
    #pragma unroll
    for (int cb = 0; cb < 8; cb++) {
        size_t idx = (size_t)cb * N_ROWS + n;
        float p = pmax_g[idx]; int pi = pidx_g[idx];
        pm[cb] = p;
        if (p > gm || (p == gm && pi < gi)) { gm = p; gi = pi; }
        rm = fmaxf(rm, prmax_g[idx]);
        c0m = fmaxf(c0m, pc0_g[idx]);
    }
    float den = 0.0f;
    #pragma unroll
    for (int cb = 0; cb < 8; cb++)
        den += psum_g[(size_t)cb * N_ROWS + n] * __expf(pm[cb] - gm);
    float lse = gm + __logf(den);

    int yv = y[n];
    int lab = (yv >= ninit_p[0]) ? -1 : yv;
    float nll, wgt;
    if (rm != -INFINITY) { nll = lse - rm; wgt = 1.0f; }
    else {                                   // all-(-inf) argmax -> col 0
        float l0 = l0arr[n];
        nll = lse - l0;
        wgt = (l0 == c0m) ? 1.0f : 0.0f;
    }
    int ypred = slab[gi];
    float li = nll * wgt * (1.0f / (float)N_ROWS);
    float ai = (ypred == lab) ? 1.0f : 0.0f;

    #pragma unroll
    for (int off = 32; off; off >>= 1) {
        li += __shfl_xor(li, off);
        ai += __shfl_xor(ai, off);
    }
    __shared__ float pl[4], pa_[4];
    if (lane == 0) { pl[w] = li; pa_[w] = ai; }
    __syncthreads();
    if (t == 0) {
        atomicAdd(&out[0], pl[0] + pl[1] + pl[2] + pl[3]);
        atomicAdd(&out[1], pa_[0] + pa_[1] + pa_[2] + pa_[3]);
    }
}

extern "C" void kernel_launch(void* const* d_in, const int* in_sizes, int n_in,
                              void* d_out, int out_size, void* d_ws, size_t ws_size,
                              hipStream_t stream) {
    const float* h      = (const float*)d_in[0];
    const float* protos = (const float*)d_in[1];
    const float* radii  = (const float*)d_in[2];
    const int*   y      = (const int*)d_in[3];
    const int*   slab   = (const int*)d_in[4];
    const int*   ninit  = (const int*)d_in[5];
    float* out = (float*)d_out;

    char* ws = (char*)d_ws;
    u16*   hb    = (u16*)(ws);                       // 16 MiB
    u16*   bb    = (u16*)(ws + 16777216);            // 1 MiB
    float* hsq   = (float*)(ws + 17825792);          // 32 KiB
    float* psq   = (float*)(ws + 17858560);          // 2 KiB
    float* pmax  = (float*)(ws + 17860608);          // 8*8192*4 = 256 KiB
    int*   pidx  = (int*)  (ws + 18122752);
    float* prmax = (float*)(ws + 18384896);
    float* pc0   = (float*)(ws + 18647040);
    float* psum  = (float*)(ws + 18909184);
    float* l0arr = (float*)(ws + 19171328);          // 32 KiB

    conv_hp<<<640, 256, 0, stream>>>(h, protos, hb, bb, hsq, psq, out);
    gemm_partials<<<512, 256, 0, stream>>>(hb, bb, hsq, psq, radii, y, slab, ninit,
                                           pmax, pidx, prmax, pc0, psum, l0arr);
    combine<<<N_ROWS / 256, 256, 0, stream>>>(pmax, pidx, prmax, pc0, psum,
                                              l0arr, y, slab, ninit, out);
}